// Round 8
// baseline (233.662 us; speedup 1.0000x reference)
//
#include <hip/hip_runtime.h>
#include <hip/hip_fp16.h>
#include <cstddef>

#define Bc   32
#define Nc   512
#define Mc   512
#define DFc  64
#define BIGC 1.0e10f
#define LOG2E_F 1.4426950408889634f
#define LN2_F   0.6931471805599453f
#define SQRT_LOG2E_F 1.2011224087864498f

typedef unsigned int uint32;

// lane l gets lane l-1's src; lane 0 gets `oldv`  (DPP wave_shr:1)
__device__ __forceinline__ float dpp_shr1(float oldv, float src) {
    return __int_as_float(__builtin_amdgcn_update_dpp(
        __float_as_int(oldv), __float_as_int(src), 0x138, 0xf, 0xf, false));
}
// shift with don't-care lane0 (single v_mov_b32_dpp)
__device__ __forceinline__ float dpp_shr1_nc(float src) {
    return __int_as_float(__builtin_amdgcn_mov_dpp(
        __float_as_int(src), 0x138, 0xf, 0xf, false));
}
__device__ __forceinline__ float rl(float v, int lane) {
    return __int_as_float(__builtin_amdgcn_readlane(__float_as_int(v), lane));
}

// Bit-trick softmin in log2 domain, MINUS 127 (the +127 is pre-folded into
// Dsk values by the dist kernel, so val = softmin3m(...) + D' is exact).
__device__ __forceinline__ float softmin3m(float a, float b, float c) {
    float mn = fminf(fminf(a, b), c);
    float mx = fmaxf(fmaxf(a, b), c);
    float md = __builtin_amdgcn_fmed3f(a, b, c);
    uint32 b1 = (uint32)fmaxf(fmaf(mn - mx, 8388608.0f, 1065353216.0f), 0.0f);
    uint32 b2 = (uint32)fmaxf(fmaf(mn - md, 8388608.0f, 1065353216.0f), 0.0f);
    float E = 1.0f + (__int_as_float(b1) + __int_as_float(b2));
    return fmaf((float)__float_as_uint(E), -1.1920929e-7f, mn);
}

// ---------------------------------------------------------------------------
// Kernel 1: distances in SCALED (x LOG2E, +127-biased) fp16 for the 2-col
// superstep scan. Tile = ((b*4 + strip)*4 + J): 128 rows x 128 cols.
//   uint4 at [tile*4096 + g*64 + l], supersteps t1=2g+1, t2=2g+2:
//     .x = half2(A@k, A@k+1)  .y = half2(B@k, B@k+1)   k = 4g-2l   (t1)
//     .z = half2(A@k2,A@k2+1) .w = half2(B@k2,B@k2+1)  k2 = 4g-2l+2 (t2)
//   A = D row 2l (strip-rel), B = row 2l+1; cols clamped to [0,127]
//   (clamped garbage is never consumed by the scan's active window).
// ---------------------------------------------------------------------------
__global__ __launch_bounds__(256) void dist_kernel(
    const float* __restrict__ X, const float* __restrict__ Y,
    uint32* __restrict__ Dsk)
{
    __shared__ __align__(16) unsigned char SMEM[34816];
    unsigned short* XsH = (unsigned short*)SMEM;            // [128][64] rotated
    unsigned short* YsH = (unsigned short*)(SMEM + 16384);  // [128][64] rotated
    uint32* P = (uint32*)SMEM;                              // [128][67] aliased

    const int b     = blockIdx.z;
    const int strip = blockIdx.y;          // 128-row band of X
    const int J     = blockIdx.x;          // 128-col band (rows of Y)
    const int tid   = threadIdx.x;

    const float* Xg = X + ((size_t)b * Nc + strip * 128) * DFc;
    const float* Yg = Y + ((size_t)b * Mc + J * 128) * DFc;

    // stage fp16 (x sqrt(LOG2E)), row-group rotation for conflict-free reads
#pragma unroll
    for (int it = 0; it < 8; ++it) {
        int e4 = it * 256 + tid;
        int n = e4 >> 4, k4 = (e4 & 15) * 4;
        float4 v = ((const float4*)Xg)[e4];
        __half2 h01 = __floats2half2_rn(v.x * SQRT_LOG2E_F, v.y * SQRT_LOG2E_F);
        __half2 h23 = __floats2half2_rn(v.z * SQRT_LOG2E_F, v.w * SQRT_LOG2E_F);
        int ho = (k4 + 8 * ((n >> 3) & 7)) & 63;
        uint2 u; u.x = *(uint32*)&h01; u.y = *(uint32*)&h23;
        *(uint2*)&XsH[n * 64 + ho] = u;
    }
#pragma unroll
    for (int it = 0; it < 8; ++it) {
        int e4 = it * 256 + tid;
        int m = e4 >> 4, k4 = (e4 & 15) * 4;
        float4 v = ((const float4*)Yg)[e4];
        __half2 h01 = __floats2half2_rn(v.x * SQRT_LOG2E_F, v.y * SQRT_LOG2E_F);
        __half2 h23 = __floats2half2_rn(v.z * SQRT_LOG2E_F, v.w * SQRT_LOG2E_F);
        int ho = (k4 + 8 * ((m >> 3) & 7)) & 63;
        uint2 u; u.x = *(uint32*)&h01; u.y = *(uint32*)&h23;
        *(uint2*)&YsH[m * 64 + ho] = u;
    }
    __syncthreads();

    const int tx = tid & 15;   // cols 8tx..8tx+7
    const int ty = tid >> 4;   // rows 8ty..8ty+7

    __half2 acc[8][8];
#pragma unroll
    for (int a = 0; a < 8; ++a)
#pragma unroll
        for (int c = 0; c < 8; ++c) acc[a][c] = __floats2half2_rn(0.f, 0.f);

    const int xrot = 8 * (ty & 7);
    const int yrot = 8 * (tx & 7);

#pragma unroll 2
    for (int k8 = 0; k8 < 8; ++k8) {
        uint4 xv[8], yvv[8];
#pragma unroll
        for (int a = 0; a < 8; ++a)
            xv[a] = *(const uint4*)&XsH[(8 * ty + a) * 64 + ((k8 * 8 + xrot) & 63)];
#pragma unroll
        for (int c = 0; c < 8; ++c)
            yvv[c] = *(const uint4*)&YsH[(8 * tx + c) * 64 + ((k8 * 8 + yrot) & 63)];
#pragma unroll
        for (int a = 0; a < 8; ++a) {
            const uint32 xa[4] = {xv[a].x, xv[a].y, xv[a].z, xv[a].w};
#pragma unroll
            for (int c = 0; c < 8; ++c) {
                const uint32 ya[4] = {yvv[c].x, yvv[c].y, yvv[c].z, yvv[c].w};
#pragma unroll
                for (int t = 0; t < 4; ++t) {
                    __half2 xd = *(const __half2*)&xa[t];
                    __half2 yd = *(const __half2*)&ya[t];
                    __half2 d = __hsub2(xd, yd);
                    acc[a][c] = __hfma2(d, d, acc[a][c]);
                }
            }
        }
    }
    __syncthreads();   // staging dead; P may alias

    // fold k-partials, add +127 bias, pack P[col][pair] = half2(rowA, rowB)
#pragma unroll
    for (int a = 0; a < 8; a += 2) {
        int p = 4 * ty + (a >> 1);
#pragma unroll
        for (int c = 0; c < 8; ++c) {
            float2 fa = __half22float2(acc[a][c]);
            float2 fb = __half22float2(acc[a + 1][c]);
            __half2 h = __floats2half2_rn(fa.x + fa.y + 127.0f,
                                          fb.x + fb.y + 127.0f);
            P[(8 * tx + c) * 67 + p] = *(uint32*)&h;
        }
    }
    __syncthreads();

    // skew gather + coalesced b128 store
    const int l = tid & 63;
    const int q = tid >> 6;
    uint4* outt = (uint4*)Dsk + (((size_t)b * 4 + strip) * 4 + J) * 4096;
    const uint32* Pl = P + l;
#pragma unroll
    for (int gi = 0; gi < 16; ++gi) {
        int g = q + 4 * gi;              // 0..63
        int ka = 4 * g - 2 * l;
        int c0 = min(max(ka,     0), 127);
        int c1 = min(max(ka + 1, 0), 127);
        int c2 = min(max(ka + 2, 0), 127);
        int c3 = min(max(ka + 3, 0), 127);
        uint32 p0 = Pl[c0 * 67];
        uint32 p1 = Pl[c1 * 67];
        uint32 p2 = Pl[c2 * 67];
        uint32 p3 = Pl[c3 * 67];
        uint4 v;
        v.x = (p0 & 0xffffu) | (p1 << 16);
        v.y = (p0 >> 16)     | (p1 & 0xffff0000u);
        v.z = (p2 & 0xffffu) | (p3 << 16);
        v.w = (p2 >> 16)     | (p3 & 0xffff0000u);
        outt[g * 64 + l] = v;
    }
}

// ---------------------------------------------------------------------------
// Kernel 2: 2-col SUPERSTEP tile-systolic scan. 128-col tiles, 4 strips,
// 1 batch/block (4 waves, 1/SIMD). Lane l owns rows 2l+1, 2l+2 (strip-rel)
// and processes col-pair (c1,c2) = (2(t-l)-1, 2(t-l)) per superstep t.
// 4 cells/superstep, chain = 3 softmins per 2 cols; one dpp-pair per
// superstep; hold-semantics registers carry state across tiles; frontier
// via Fodd/Fev VGPRs + readlane inject (phase 1) / b32-pair publish
// (phase 2). Critical path: (wxl + Jcap + 1) <= 7 tiles x 127 supersteps.
// ---------------------------------------------------------------------------
#define SSTEP(T, dAw, dBw, PH1)                                            \
  {                                                                        \
    float2 fA = __half22float2(*(const __half2*)&(dAw));                   \
    float2 fB = __half22float2(*(const __half2*)&(dBw));                   \
    float u1, u2;                                                          \
    if (PH1) {                                                             \
      u1 = dpp_shr1(rl(Fodd, (T) - 1), pub1);                              \
      u2 = dpp_shr1(rl(Fev,  (T) - 1), curB);                              \
    } else {                                                               \
      u1 = dpp_shr1_nc(pub1);                                              \
      u2 = dpp_shr1_nc(curB);                                              \
    }                                                                      \
    float A1 = softmin3m(diagA, u1, curA) + fA.x;                          \
    float A2 = softmin3m(u1, u2, A1) + fA.y;                               \
    float B1 = softmin3m(curA, A1, curB) + fB.x;                           \
    float B2 = softmin3m(A1, A2, B1) + fB.y;                               \
    float vs1 = useB ? B1 : A1;                                            \
    float vs2 = useB ? B2 : A2;                                            \
    float vsc = useC2 ? vs2 : vs1;                                         \
    capv = ((T) == scap) ? vsc : capv;                                     \
    bool act = (PH1) ? (l < (T)) : (l >= (T) - 64);                        \
    pub1  = act ? B1 : curB;   /* reads curB BEFORE update */              \
    curA  = act ? A2 : curA;                                               \
    curB  = act ? B2 : curB;                                               \
    diagA = u2;                                                            \
    if (!(PH1)) { wbase[2 * (T) - 127] = B1; wbase[2 * (T) - 126] = B2; }  \
  }

__global__ __launch_bounds__(256) void scan_kernel(
    const uint32* __restrict__ Dsk,
    const int* __restrict__ X_len, const int* __restrict__ Y_len,
    float* __restrict__ out)
{
    __shared__ __align__(16) float Frow[4][520];
    __shared__ float dumpArr[136];

    const int tid = threadIdx.x;
    const int l  = tid & 63;
    const int wl = __builtin_amdgcn_readfirstlane(tid >> 6);  // strip 0..3
    const int bb = blockIdx.x;

    const int xl = X_len[bb], yl = Y_len[bb];
    const int wxl  = (xl - 1) >> 7;           // capture strip
    const int iw   = (xl - 1) & 127;
    const int lcap = iw >> 1;                 // capture lane
    const int useB = iw & 1;                  // row parity (A/B)
    const int Jcap = (yl - 1) >> 7;           // capture tile (128-col)
    const int ycol = yl - (Jcap << 7);        // 1..128
    const int useC2 = 1 - (ycol & 1);         // even rel-col -> second cell
    const int tcap = ((ycol + 1) >> 1) + lcap;   // in [1,127]
    const int kmax = wxl + Jcap;              // <= 6

    const bool is63 = (l == 63);

    if (l == 0) Frow[wl][0] = BIGC;           // col-0 border for f0 at J=0
    __syncthreads();

    float curA = BIGC, curB = BIGC, pub1 = BIGC;
    float diagA = BIGC;
    float capv = 0.0f;

    for (int k = 0; k <= kmax; ++k) {
        int J = k - wl;
        if (wl <= wxl && 0 <= J && J <= Jcap) {
            const int j0 = J << 7;
            float Fodd, Fev, f0;
            if (wl > 0) {
                Fodd = Frow[wl - 1][j0 + 1 + 2 * l];   // odd rel-cols 1..127
                Fev  = Frow[wl - 1][j0 + 2 + 2 * l];   // even rel-cols 2..128
                f0   = Frow[wl - 1][j0];               // diag seed col j0
            } else {
                Fodd = BIGC; Fev = BIGC;
                f0 = (J == 0) ? 0.0f : BIGC;           // R[0][0] = 0
            }
            diagA = (l == 0) ? f0 : diagA;

            const uint4* tp = (const uint4*)Dsk +
                ((((size_t)bb * 4 + wl) * 4) + J) * 4096 + l;
            const int scap = (wl == wxl && J == Jcap) ? tcap : -1000;
            float* wbase = is63 ? (&Frow[wl][j0]) : (dumpArr + 4);

            uint4 dreg[4];
            dreg[0] = tp[0];   dreg[1] = tp[64];
            dreg[2] = tp[128]; dreg[3] = tp[192];

            // ---- phase 1: g 0..31 (t = 1..64): lane0 inject, no stores ----
#pragma unroll 1
            for (int m = 0; m < 8; ++m) {
#pragma unroll
                for (int q = 0; q < 4; ++q) {
                    const int g = m * 4 + q;
                    uint4 dc = dreg[q];
                    dreg[q] = tp[(g + 4) * 64];
                    SSTEP(2 * g + 1, dc.x, dc.y, true)
                    SSTEP(2 * g + 2, dc.z, dc.w, true)
                }
            }
            // t=64 boundary publish: lane63 (just activated) cols 1,2
            wbase[1] = pub1;
            wbase[2] = curB;

            // ---- phase 2: g 32..59 (t = 65..120): no inject, store pair ----
#pragma unroll 1
            for (int m = 8; m < 15; ++m) {
#pragma unroll
                for (int q = 0; q < 4; ++q) {
                    const int g = m * 4 + q;
                    uint4 dc = dreg[q];
                    dreg[q] = tp[(g + 4) * 64];
                    SSTEP(2 * g + 1, dc.x, dc.y, false)
                    SSTEP(2 * g + 2, dc.z, dc.w, false)
                }
            }
            // ---- peel: g 60..63 (t = 121..127; t=128 skipped) ----
#pragma unroll
            for (int q = 0; q < 4; ++q) {
                const int g = 60 + q;
                uint4 dc = dreg[q];
                SSTEP(2 * g + 1, dc.x, dc.y, false)
                if (g < 63) { SSTEP(2 * g + 2, dc.z, dc.w, false) }
            }
        }
        __syncthreads();
    }

    if (wl == wxl) {
        float o = rl(capv, lcap);
        if (l == 0) out[bb] = o * LN2_F;
    }
}

extern "C" void kernel_launch(void* const* d_in, const int* in_sizes, int n_in,
                              void* d_out, int out_size, void* d_ws, size_t ws_size,
                              hipStream_t stream)
{
    const float* X  = (const float*)d_in[0];
    const float* Y  = (const float*)d_in[1];
    const int*   xl = (const int*)d_in[2];
    const int*   yl = (const int*)d_in[3];
    float* out = (float*)d_out;
    uint32* Dsk = (uint32*)d_ws;   // 32 b * 4 strips * 4 J * 64 KB = 32 MB

    dist_kernel<<<dim3(4, 4, Bc), 256, 0, stream>>>(X, Y, Dsk);
    scan_kernel<<<Bc, 256, 0, stream>>>(Dsk, xl, yl, out);
}